// Round 1
// baseline (11792.003 us; speedup 1.0000x reference)
//
#include <hip/hip_runtime.h>
#include <cmath>

// ---------------------------------------------------------------------------
// MultiSeq2SeqPredict on MI355X: single persistent cooperative kernel.
// 3 GRU encoders (L=64) -> attention decoder (greedy, 64 steps) -> log_softmax.
// All matvecs fp32, wave-per-row dot products with DPP (VALU-pipe) reductions.
// Grid-wide sync: slotted barrier + WG0-master with serial "callback" stage.
// ---------------------------------------------------------------------------

#define GRID  256
#define TPB   256
#define HD    1024
#define VC    32000
#define LS    64
#define EOS_TOK 1

#define CTRL_BYTES 32768
// float offsets inside workspace (after control block)
#define F_H      0          // 1024  decoder hidden (committed)   [memset 0]
#define F_H2     1024       // 1024  decoder hidden candidate
#define F_X      2048       // 1024  decoder GRU input x
#define F_GH     3072       // 3072  dec_W_hh @ h + b_hh (speculative)
#define F_SCH    6144       // 64    W_attn[:,H:] @ h (speculative)
#define F_AW     6208       // 64    attention weights of current step
#define F_PARTV  6272       // 256   per-WG argmax partial values
#define F_M      6528       // 65536 M = W_comb[:,H:] @ enc_outs^T   [1024][64]
#define F_ENCOUT 72064      // 65536 combined encoder outputs [64][1024]
#define F_GI     137600     // 589824 gi = enc_W_ih@x + b_ih  [3][64][3072]
#define F_OUTS   727424     // 196608 encoder hidden per step [3][64][1024]
#define F_WAE    924032     // 2048000 WaE = W_attn[:,:H] @ dec_emb^T [64][V]
#define WS_FLOATS 2972032

struct __align__(64) Ctrl {
  int epoch; int _p0[15];
  int arrive[GRID * 16];       // one 64B-padded slot per WG
  int tok; int done; int copy; int _p1[13];
  int partIdx[GRID];
};

typedef struct { float4 v[4]; } V16;   // one wave covers 1024 floats: lane*4 + c*256

__device__ __forceinline__ V16 ldv(const float* __restrict__ p, int lane) {
  V16 r;
#pragma unroll
  for (int c = 0; c < 4; ++c)
    r.v[c] = *(const float4*)(p + c * 256 + lane * 4);
  return r;
}

__device__ __forceinline__ float dot16(const V16& a, const V16& b) {
  float s = 0.f;
#pragma unroll
  for (int c = 0; c < 4; ++c) {
    s = fmaf(a.v[c].x, b.v[c].x, s);
    s = fmaf(a.v[c].y, b.v[c].y, s);
    s = fmaf(a.v[c].z, b.v[c].z, s);
    s = fmaf(a.v[c].w, b.v[c].w, s);
  }
  return s;
}

// DPP wave64 sum: VALU pipe (not LDS like __shfl). Full sum lands in lane 63.
template <int DCTL>
__device__ __forceinline__ float dppadd(float v) {
  int t = __builtin_amdgcn_update_dpp(0, __builtin_bit_cast(int, v), DCTL, 0xF, 0xF, true);
  return v + __builtin_bit_cast(float, t);
}
__device__ __forceinline__ float dpp_sum63(float v) {
  v = dppadd<0x111>(v);  // row_shr:1
  v = dppadd<0x112>(v);  // row_shr:2
  v = dppadd<0x114>(v);  // row_shr:4
  v = dppadd<0x118>(v);  // row_shr:8   -> lane15/31/47/63 have row sums
  v = dppadd<0x142>(v);  // row_bcast15 -> lane31 = 0..31, lane63 = 32..63
  v = dppadd<0x143>(v);  // row_bcast31 -> lane63 = total
  return v;
}

__device__ __forceinline__ float gru_out(float gir, float giz, float gin,
                                         float ghr, float ghz, float ghn, float hp) {
  float r = 1.f / (1.f + expf(-(gir + ghr)));
  float z = 1.f / (1.f + expf(-(giz + ghz)));
  float n = tanhf(gin + r * ghn);
  return (1.f - z) * n + z * hp;
}

// ---- slotted grid barrier: workers release-store a slot; WG0 sweeps in parallel.
__device__ __forceinline__ void bar_worker(Ctrl* c, int t) {
  __syncthreads();
  if (threadIdx.x == 0) {
    __hip_atomic_store(&c->arrive[blockIdx.x * 16], t, __ATOMIC_RELEASE, __HIP_MEMORY_SCOPE_AGENT);
    while (__hip_atomic_load(&c->epoch, __ATOMIC_ACQUIRE, __HIP_MEMORY_SCOPE_AGENT) < t)
      __builtin_amdgcn_s_sleep(2);
  }
  __syncthreads();
}
__device__ __forceinline__ void bar_master_wait(Ctrl* c, int t) {
  __syncthreads();
  if (threadIdx.x > 0) {   // thread i watches WG i's slot
    while (__hip_atomic_load(&c->arrive[threadIdx.x * 16], __ATOMIC_ACQUIRE, __HIP_MEMORY_SCOPE_AGENT) < t)
      __builtin_amdgcn_s_sleep(1);
  }
  __syncthreads();
}
__device__ __forceinline__ void bar_master_release(Ctrl* c, int t) {
  __syncthreads();
  if (threadIdx.x == 0)
    __hip_atomic_store(&c->epoch, t, __ATOMIC_RELEASE, __HIP_MEMORY_SCOPE_AGENT);
  __syncthreads();
}

// ---- serial per-step stage, run by WG0 inside the barrier (prepares step s).
__device__ void decode_prepare(int s, Ctrl* c, float* __restrict__ fb,
                               const float* __restrict__ b_attn,
                               float* __restrict__ out_attns,
                               float* __restrict__ out_toks) {
  const int tid = threadIdx.x;
  __shared__ float s_v[TPB];
  __shared__ int   s_i[TPB];
  int frozen = 0;
  if (s > 0) {
    int done_entry = c->done;      // == done_{s-2} (state at entry of step s-1)
    if (!done_entry) {
      // finalize argmax of step s-1 over 256 WG partials (ties -> lowest index)
      s_v[tid] = fb[F_PARTV + tid];
      s_i[tid] = c->partIdx[tid];
      __syncthreads();
      for (int st = TPB / 2; st > 0; st >>= 1) {
        if (tid < st) {
          float ov = s_v[tid + st]; int oi = s_i[tid + st];
          if (ov > s_v[tid] || (ov == s_v[tid] && oi < s_i[tid])) { s_v[tid] = ov; s_i[tid] = oi; }
        }
        __syncthreads();
      }
      int nxt = s_i[0];
      if (tid == 0) {
        out_toks[s - 1] = (float)nxt;   // tok_out = nxt (done was false)
        c->tok = nxt;
        if (nxt == EOS_TOK) c->done = 1;
      }
      // commit h <- h2 (valid also at the EOS-transition step)
      for (int j = tid; j < HD; j += TPB) fb[F_H + j] = fb[F_H2 + j];
    } else {
      // fully frozen: outputs of step s are copies of step s-1
      frozen = 1;
      if (tid == 0) { out_toks[s - 1] = (float)c->tok; c->copy = 1; }
      if (s < LS && tid < LS) out_attns[s * LS + tid] = out_attns[(s - 1) * LS + tid];
    }
  }
  if (s >= LS || frozen) return;
  __syncthreads();
  int tok = c->tok;
  if (tid < LS) {   // wave 0: scores -> softmax -> aw
    float sc = fb[F_WAE + (size_t)tid * VC + tok] + fb[F_SCH + tid] + b_attn[tid];
    float m = sc;
    for (int off = 32; off > 0; off >>= 1) m = fmaxf(m, __shfl_xor(m, off, 64));
    float ex = expf(sc - m);
    float sum = ex;
    for (int off = 32; off > 0; off >>= 1) sum += __shfl_xor(sum, off, 64);
    float a = ex / sum;
    fb[F_AW + tid] = a;
    out_attns[s * LS + tid] = a;
  }
}

__global__ void __launch_bounds__(TPB, 1)
seq2seq_kernel(const int* __restrict__ qids, const int* __restrict__ cand,
               const float* __restrict__ enc_emb, const float* __restrict__ enc_Wih,
               const float* __restrict__ enc_Whh, const float* __restrict__ enc_bih,
               const float* __restrict__ enc_bhh, const float* __restrict__ dec_emb,
               const float* __restrict__ W_attn, const float* __restrict__ b_attn,
               const float* __restrict__ W_comb, const float* __restrict__ b_comb,
               const float* __restrict__ dWih, const float* __restrict__ dWhh,
               const float* __restrict__ dbih, const float* __restrict__ dbhh,
               const float* __restrict__ Wout, const float* __restrict__ bout,
               float* __restrict__ out, float* __restrict__ ws) {
  Ctrl* c = (Ctrl*)ws;
  float* fb = (float*)((char*)ws + CTRL_BYTES);
  const int tid = threadIdx.x;
  const int wg = blockIdx.x;
  const int wid = tid >> 6;
  const int lane = tid & 63;
  float* out_attns = out + (size_t)LS * VC;
  float* out_toks = out_attns + LS * LS;
  int bt = 0;

  // ================= P1: gi GEMM (3 encoders) + WaE precompute ==============
  {
    int gw = wg * 4 + wid;
#pragma unroll 1
    for (int task = gw; task < 2304 + VC; task += GRID * 4) {
      if (task < 2304) {   // 4 rows of enc_W_ih x 64 timesteps
        int r0 = task * 4;
        int e = r0 / 3072;
        int rL = r0 - e * 3072;
        const float* Wr = enc_Wih + (size_t)e * 3 * HD * HD + (size_t)rL * HD;
        V16 w0 = ldv(Wr, lane), w1 = ldv(Wr + HD, lane);
        V16 w2 = ldv(Wr + 2 * HD, lane), w3 = ldv(Wr + 3 * HD, lane);
        const int* ids = (e == 0) ? qids : (cand + (e - 1) * LS);
        float b0 = enc_bih[e * 3 * HD + rL + 0];
        float b1 = enc_bih[e * 3 * HD + rL + 1];
        float b2 = enc_bih[e * 3 * HD + rL + 2];
        float b3 = enc_bih[e * 3 * HD + rL + 3];
#pragma unroll 1
        for (int t = 0; t < LS; ++t) {
          int tk = ids[t];
          V16 xv = ldv(enc_emb + ((size_t)e * VC + tk) * HD, lane);
          float s0 = dpp_sum63(dot16(w0, xv));
          float s1 = dpp_sum63(dot16(w1, xv));
          float s2 = dpp_sum63(dot16(w2, xv));
          float s3 = dpp_sum63(dot16(w3, xv));
          if (lane == 63) {
            float4 st = make_float4(s0 + b0, s1 + b1, s2 + b2, s3 + b3);
            *(float4*)(fb + F_GI + (size_t)(e * LS + t) * 3 * HD + rL) = st;
          }
        }
      } else {             // WaE column for one vocab token
        int cc = task - 2304;
        V16 ev = ldv(dec_emb + (size_t)cc * HD, lane);
#pragma unroll 1
        for (int k = 0; k < LS; ++k) {
          float s = dpp_sum63(dot16(ldv(W_attn + (size_t)k * 2 * HD, lane), ev));
          if (lane == 63) fb[F_WAE + (size_t)k * VC + cc] = s;
        }
      }
    }
  }
  bt++; if (wg == 0) { bar_master_wait(c, bt); bar_master_release(c, bt); } else bar_worker(c, bt);

  // ================= P2: encoder recurrence (64 steps, 3 encoders) ==========
#pragma unroll 1
  for (int t = 0; t < LS; ++t) {
    int gw = wg * 4 + wid;   // 1024 waves, 3 (e,j) entities each
#pragma unroll 1
    for (int q = 0; q < 3; ++q) {
      int ent = gw * 3 + q;
      int e = ent >> 10, j = ent & (HD - 1);
      const float* Whh = enc_Whh + (size_t)e * 3 * HD * HD;
      float ghr = 0.f, ghz = 0.f, ghn = 0.f, hp = 0.f;
      if (t > 0) {
        const float* hprev = fb + F_OUTS + (size_t)(e * LS + (t - 1)) * HD;
        V16 hv = ldv(hprev, lane);
        ghr = dpp_sum63(dot16(ldv(Whh + (size_t)j * HD, lane), hv));
        ghz = dpp_sum63(dot16(ldv(Whh + (size_t)(HD + j) * HD, lane), hv));
        ghn = dpp_sum63(dot16(ldv(Whh + (size_t)(2 * HD + j) * HD, lane), hv));
        hp = hprev[j];
      }
      if (lane == 63) {
        ghr += enc_bhh[e * 3 * HD + j];
        ghz += enc_bhh[e * 3 * HD + HD + j];
        ghn += enc_bhh[e * 3 * HD + 2 * HD + j];
        const float* gi = fb + F_GI + (size_t)(e * LS + t) * 3 * HD;
        fb[F_OUTS + (size_t)(e * LS + t) * HD + j] =
            gru_out(gi[j], gi[HD + j], gi[2 * HD + j], ghr, ghz, ghn, hp);
      }
    }
    bt++; if (wg == 0) { bar_master_wait(c, bt); bar_master_release(c, bt); } else bar_worker(c, bt);
  }

  // ===== P2b1: combine encoder outputs; init gh=b_hh, scoresH=0 =============
  {
    int gt = wg * TPB + tid;   // 0..65535
    float o0 = fb[F_OUTS + gt];
    float o1 = fb[F_OUTS + 65536 + gt];
    float o2 = fb[F_OUTS + 131072 + gt];
    fb[F_ENCOUT + gt] = o0 + 0.5f * (o1 + o2);
    if (gt < 3 * HD) fb[F_GH + gt] = dbhh[gt];   // W_hh @ 0 + b_hh
    if (gt < LS) fb[F_SCH + gt] = 0.f;           // W_attn[:,H:] @ 0
  }
  bt++; if (wg == 0) { bar_master_wait(c, bt); bar_master_release(c, bt); } else bar_worker(c, bt);

  // ===== P2b2: M = W_comb[:, H:] @ enc_outs^T  (then prepare step 0) ========
  {
    int r = wg * 4 + wid;
    V16 wr = ldv(W_comb + (size_t)r * 2 * HD + HD, lane);
#pragma unroll 1
    for (int t = 0; t < LS; ++t) {
      float s = dpp_sum63(dot16(wr, ldv(fb + F_ENCOUT + (size_t)t * HD, lane)));
      if (lane == 63) fb[F_M + r * LS + t] = s;
    }
  }
  bt++;
  if (wg == 0) { bar_master_wait(c, bt); decode_prepare(0, c, fb, b_attn, out_attns, out_toks); bar_master_release(c, bt); }
  else bar_worker(c, bt);

  // ================= decode: 64 steps, 3 barriers each ======================
#pragma unroll 1
  for (int s = 0; s < LS; ++s) {
    int cp = c->copy;
    // ---- Phase X: x = relu(W_comb[:, :H] @ e + M @ aw + b_comb)
    if (!cp) {
      int tok = c->tok;
      int r = wg * 4 + wid;
      V16 ev = ldv(dec_emb + (size_t)tok * HD, lane);
      V16 wr = ldv(W_comb + (size_t)r * 2 * HD, lane);
      float p = dot16(wr, ev);
      if (lane < 16) {
        float4 m4 = *(const float4*)(fb + F_M + r * LS + lane * 4);
        float4 a4 = *(const float4*)(fb + F_AW + lane * 4);
        p = fmaf(m4.x, a4.x, p); p = fmaf(m4.y, a4.y, p);
        p = fmaf(m4.z, a4.z, p); p = fmaf(m4.w, a4.w, p);
      }
      float sum = dpp_sum63(p);
      if (lane == 63) fb[F_X + r] = fmaxf(sum + b_comb[r], 0.f);
    }
    bt++; if (wg == 0) { bar_master_wait(c, bt); bar_master_release(c, bt); } else bar_worker(c, bt);

    // ---- Phase G: gi = dec_W_ih @ x; h2 = GRU(h, x)
    if (!cp) {
      int j = wg * 4 + wid;
      V16 xv = ldv(fb + F_X, lane);
      float g0 = dpp_sum63(dot16(ldv(dWih + (size_t)j * HD, lane), xv));
      float g1 = dpp_sum63(dot16(ldv(dWih + (size_t)(HD + j) * HD, lane), xv));
      float g2 = dpp_sum63(dot16(ldv(dWih + (size_t)(2 * HD + j) * HD, lane), xv));
      if (lane == 63) {
        g0 += dbih[j]; g1 += dbih[HD + j]; g2 += dbih[2 * HD + j];
        fb[F_H2 + j] = gru_out(g0, g1, g2, fb[F_GH + j], fb[F_GH + HD + j],
                               fb[F_GH + 2 * HD + j], fb[F_H + j]);
      }
    }
    bt++; if (wg == 0) { bar_master_wait(c, bt); bar_master_release(c, bt); } else bar_worker(c, bt);

    // ---- Phase L: logits = W_out@h2 + b_out (+ speculative gh/scoresH on h2)
    if (cp) {
      int i = wg * 125 + tid;
      if (tid < 125) out[(size_t)s * VC + i] = out[(size_t)(s - 1) * VC + i];
    } else {
      V16 hv = ldv(fb + F_H2, lane);
      for (int q = wid; q < 12; q += 4) {   // speculative dec_W_hh @ h2 + b_hh
        int row = wg * 12 + q;
        float g = dpp_sum63(dot16(ldv(dWhh + (size_t)row * HD, lane), hv));
        if (lane == 63) fb[F_GH + row] = g + dbhh[row];
      }
      if (wg < LS && wid == 0) {            // speculative W_attn[:,H:] @ h2
        float g = dpp_sum63(dot16(ldv(W_attn + (size_t)wg * 2 * HD + HD, lane), hv));
        if (lane == 63) fb[F_SCH + wg] = g;
      }
      int base = wg * 125;
      int lo = wid * 32;
      int hi = (lo + 32 < 125) ? lo + 32 : 125;
      float bestv = -3.0e38f; int bestr = 0x7FFFFFFF;
#pragma unroll 1
      for (int rr = lo; rr < hi; rr += 2) {
        int r1 = base + rr;
        bool two = (rr + 1 < hi);
        int r2 = two ? r1 + 1 : r1;
        float p1 = dot16(ldv(Wout + (size_t)r1 * HD, lane), hv);
        float p2 = dot16(ldv(Wout + (size_t)r2 * HD, lane), hv);
        float s1 = dpp_sum63(p1);
        float s2 = dpp_sum63(p2);
        if (lane == 63) {
          s1 += bout[r1];
          out[(size_t)s * VC + r1] = s1;
          if (s1 > bestv) { bestv = s1; bestr = r1; }
          if (two) {
            s2 += bout[r2];
            out[(size_t)s * VC + r2] = s2;
            if (s2 > bestv) { bestv = s2; bestr = r2; }
          }
        }
      }
      __shared__ float s_lv[4]; __shared__ int s_li[4];
      if (lane == 63) { s_lv[wid] = bestv; s_li[wid] = bestr; }
      __syncthreads();
      if (tid == 0) {
        float bv = s_lv[0]; int bi = s_li[0];
#pragma unroll
        for (int q2 = 1; q2 < 4; ++q2)
          if (s_lv[q2] > bv || (s_lv[q2] == bv && s_li[q2] < bi)) { bv = s_lv[q2]; bi = s_li[q2]; }
        fb[F_PARTV + wg] = bv;
        c->partIdx[wg] = bi;
      }
    }
    bt++;
    if (wg == 0) { bar_master_wait(c, bt); decode_prepare(s + 1, c, fb, b_attn, out_attns, out_toks); bar_master_release(c, bt); }
    else bar_worker(c, bt);
  }

  // ================= P4: in-place log_softmax per step row ==================
  if (wg < LS) {
    __shared__ float s_red[TPB];
    float* row = out + (size_t)wg * VC;
    float m = -3.0e38f;
    for (int i = tid; i < VC; i += TPB) m = fmaxf(m, row[i]);
    s_red[tid] = m; __syncthreads();
    for (int st = TPB / 2; st > 0; st >>= 1) {
      if (tid < st) s_red[tid] = fmaxf(s_red[tid], s_red[tid + st]);
      __syncthreads();
    }
    float rowmax = s_red[0]; __syncthreads();
    float sum = 0.f;
    for (int i = tid; i < VC; i += TPB) sum += expf(row[i] - rowmax);
    s_red[tid] = sum; __syncthreads();
    for (int st = TPB / 2; st > 0; st >>= 1) {
      if (tid < st) s_red[tid] += s_red[tid + st];
      __syncthreads();
    }
    float lse = rowmax + logf(s_red[0]);
    __syncthreads();
    for (int i = tid; i < VC; i += TPB) row[i] -= lse;
  }
}

extern "C" void kernel_launch(void* const* d_in, const int* in_sizes, int n_in,
                              void* d_out, int out_size, void* d_ws, size_t ws_size,
                              hipStream_t stream) {
  (void)in_sizes; (void)n_in; (void)out_size; (void)ws_size;
  // zero barrier state + decoder state + h_cur (first 1024 floats of fb)
  hipMemsetAsync(d_ws, 0, CTRL_BYTES + HD * sizeof(float), stream);

  const int* qids = (const int*)d_in[0];
  const int* cand = (const int*)d_in[1];
  const float* enc_emb = (const float*)d_in[2];
  const float* enc_Wih = (const float*)d_in[3];
  const float* enc_Whh = (const float*)d_in[4];
  const float* enc_bih = (const float*)d_in[5];
  const float* enc_bhh = (const float*)d_in[6];
  const float* dec_emb = (const float*)d_in[7];
  const float* W_attn = (const float*)d_in[8];
  const float* b_attn = (const float*)d_in[9];
  const float* W_comb = (const float*)d_in[10];
  const float* b_comb = (const float*)d_in[11];
  const float* dWih = (const float*)d_in[12];
  const float* dWhh = (const float*)d_in[13];
  const float* dbih = (const float*)d_in[14];
  const float* dbhh = (const float*)d_in[15];
  const float* Wout = (const float*)d_in[16];
  const float* bout = (const float*)d_in[17];
  float* outp = (float*)d_out;
  float* wsp = (float*)d_ws;

  void* args[] = { &qids, &cand, &enc_emb, &enc_Wih, &enc_Whh, &enc_bih, &enc_bhh,
                   &dec_emb, &W_attn, &b_attn, &W_comb, &b_comb, &dWih, &dWhh,
                   &dbih, &dbhh, &Wout, &bout, &outp, &wsp };
  hipLaunchCooperativeKernel(reinterpret_cast<void*>(seq2seq_kernel),
                             dim3(GRID), dim3(TPB), args, 0, stream);
}

// Round 2
// 3862.798 us; speedup vs baseline: 3.0527x; 3.0527x over previous
//
#include <hip/hip_runtime.h>
#include <cmath>

// ---------------------------------------------------------------------------
// MultiSeq2SeqPredict on MI355X: single persistent cooperative kernel.
// R2: fence-free grid barriers. All cross-WG mutable data goes through
// relaxed SYSTEM-scope atomics (sc0 sc1 cache-bypass, coherent at Infinity
// Cache) so barriers need NO buffer_wbl2/buffer_inv (the R1 11.8ms pathology:
// ~260 barriers x ~43us of per-WG L2 flash writeback/invalidate).
// Read-only weights stay on the normal cached path.
// ---------------------------------------------------------------------------

#define GRID  256
#define TPB   256
#define HD    1024
#define VC    32000
#define LS    64
#define EOS_TOK 1

#define CTRL_BYTES 32768
// float offsets inside workspace (after control block)
#define F_H      0          // 2048  decoder hidden ping-pong [s&1]   [memset 0]
#define F_X      2048       // 1024  decoder GRU input x
#define F_GH     3072       // 3072  dec_W_hh @ h + b_hh (speculative)
#define F_SCH    6144       // 64    W_attn[:,H:] @ h (speculative)
#define F_AW     6208       // 64    attention weights of current step
#define F_PARTV  6272       // 256   per-WG argmax partial values
#define F_M      6528       // 65536 M = W_comb[:,H:] @ enc_outs^T   [1024][64]
#define F_ENCOUT 72064      // 65536 combined encoder outputs [64][1024]
#define F_GI     137600     // 589824 gi = enc_W_ih@x + b_ih  [3][64][3072]
#define F_OUTS   727424     // 196608 encoder hidden per step [3][64][1024]
#define F_WAE    924032     // 2048000 WaE token-major: [V][64]
#define WS_FLOATS 2972032

struct __align__(64) Ctrl {
  int epoch; int _p0[15];
  int arrive[GRID * 16];       // one 64B-padded slot per WG
  int tok; int done; int copy; int _p1[13];
  int partIdx[GRID];
};

// ---- relaxed system-scope (cache-bypassing, IC-coherent) accessors --------
#define SSC __HIP_MEMORY_SCOPE_SYSTEM
__device__ __forceinline__ int  ld_rlx(const int* p) {
  return __hip_atomic_load(p, __ATOMIC_RELAXED, SSC);
}
__device__ __forceinline__ void st_rlx(int* p, int v) {
  __hip_atomic_store(p, v, __ATOMIC_RELAXED, SSC);
}
__device__ __forceinline__ float ld_f(const float* p) {
  unsigned u = __hip_atomic_load((const unsigned*)p, __ATOMIC_RELAXED, SSC);
  return __builtin_bit_cast(float, u);
}
__device__ __forceinline__ void st_f(float* p, float v) {
  __hip_atomic_store((unsigned*)p, __builtin_bit_cast(unsigned, v), __ATOMIC_RELAXED, SSC);
}
__device__ __forceinline__ float2 ld_f2(const float* p) {
  unsigned long long u =
      __hip_atomic_load((const unsigned long long*)p, __ATOMIC_RELAXED, SSC);
  return __builtin_bit_cast(float2, u);
}
__device__ __forceinline__ void st_f2(float* p, float2 v) {
  __hip_atomic_store((unsigned long long*)p,
                     __builtin_bit_cast(unsigned long long, v),
                     __ATOMIC_RELAXED, SSC);
}

typedef struct { float4 v[4]; } V16;   // one wave covers 1024 floats

__device__ __forceinline__ V16 ldv(const float* __restrict__ p, int lane) {
  V16 r;
#pragma unroll
  for (int c = 0; c < 4; ++c)
    r.v[c] = *(const float4*)(p + c * 256 + lane * 4);
  return r;
}

__device__ __forceinline__ float dot16(const V16& a, const V16& b) {
  float s = 0.f;
#pragma unroll
  for (int c = 0; c < 4; ++c) {
    s = fmaf(a.v[c].x, b.v[c].x, s);
    s = fmaf(a.v[c].y, b.v[c].y, s);
    s = fmaf(a.v[c].z, b.v[c].z, s);
    s = fmaf(a.v[c].w, b.v[c].w, s);
  }
  return s;
}

// DPP wave64 sum on the VALU pipe; full sum lands in lane 63.
template <int DCTL>
__device__ __forceinline__ float dppadd(float v) {
  int t = __builtin_amdgcn_update_dpp(0, __builtin_bit_cast(int, v), DCTL, 0xF, 0xF, true);
  return v + __builtin_bit_cast(float, t);
}
__device__ __forceinline__ float dpp_sum63(float v) {
  v = dppadd<0x111>(v);
  v = dppadd<0x112>(v);
  v = dppadd<0x114>(v);
  v = dppadd<0x118>(v);
  v = dppadd<0x142>(v);
  v = dppadd<0x143>(v);
  return v;
}
__device__ __forceinline__ float bcast63(float v) {
  return __builtin_bit_cast(float,
      __builtin_amdgcn_readlane(__builtin_bit_cast(int, v), 63));
}

__device__ __forceinline__ float gru_out(float gir, float giz, float gin,
                                         float ghr, float ghz, float ghn, float hp) {
  float r = 1.f / (1.f + expf(-(gir + ghr)));
  float z = 1.f / (1.f + expf(-(giz + ghz)));
  float n = tanhf(gin + r * ghn);
  return (1.f - z) * n + z * hp;
}

// ---- fence-free slotted grid barrier --------------------------------------
__device__ __forceinline__ void bar_worker(Ctrl* c, int t) {
  __syncthreads();                       // compiler drains vmcnt before s_barrier
  if (threadIdx.x == 0) {
    __builtin_amdgcn_s_waitcnt(0);       // belt-and-suspenders for this wave
    st_rlx(&c->arrive[blockIdx.x * 16], t);
    while (ld_rlx(&c->epoch) < t) __builtin_amdgcn_s_sleep(4);
  }
  __syncthreads();
}
__device__ __forceinline__ void bar_master_wait(Ctrl* c, int t) {
  __syncthreads();
  if (threadIdx.x > 0) {                 // thread i watches WG i's slot
    while (ld_rlx(&c->arrive[threadIdx.x * 16]) < t) __builtin_amdgcn_s_sleep(1);
  }
  __syncthreads();
}
__device__ __forceinline__ void bar_master_release(Ctrl* c, int t) {
  __syncthreads();                       // drains master's serial-stage stores
  if (threadIdx.x == 0) {
    __builtin_amdgcn_s_waitcnt(0);
    st_rlx(&c->epoch, t);
  }
  __syncthreads();
}

// ---- serial per-step stage, run by WG0 inside the barrier (prepares step s).
__device__ void decode_prepare(int s, Ctrl* c, float* __restrict__ fb,
                               const float* __restrict__ b_attn,
                               float* __restrict__ out_attns,
                               float* __restrict__ out_toks) {
  const int tid = threadIdx.x;
  __shared__ float s_v[TPB];
  __shared__ int   s_i[TPB];
  int frozen = 0;
  if (s > 0) {
    int done_entry = ld_rlx(&c->done);   // state at entry of step s-1
    if (!done_entry) {
      // finalize argmax of step s-1 over 256 WG partials (ties -> lowest idx)
      s_v[tid] = ld_f(fb + F_PARTV + tid);
      s_i[tid] = ld_rlx(&c->partIdx[tid]);
      __syncthreads();
      for (int st = TPB / 2; st > 0; st >>= 1) {
        if (tid < st) {
          float ov = s_v[tid + st]; int oi = s_i[tid + st];
          if (ov > s_v[tid] || (ov == s_v[tid] && oi < s_i[tid])) { s_v[tid] = ov; s_i[tid] = oi; }
        }
        __syncthreads();
      }
      int nxt = s_i[0];
      if (tid == 0) {
        out_toks[s - 1] = (float)nxt;
        st_rlx(&c->tok, nxt);
        if (nxt == EOS_TOK) st_rlx(&c->done, 1);
      }
    } else {
      // fully frozen: outputs of step s are copies of step s-1
      frozen = 1;
      if (tid == 0) { out_toks[s - 1] = (float)ld_rlx(&c->tok); st_rlx(&c->copy, 1); }
      if (s < LS && tid < LS) out_attns[s * LS + tid] = out_attns[(s - 1) * LS + tid];
    }
  }
  if (s >= LS || frozen) return;
  __syncthreads();
  int tok = ld_rlx(&c->tok);
  if (tid < LS) {   // wave 0: scores -> softmax -> aw  (WaE is token-major)
    float sc = fb[F_WAE + (size_t)tok * LS + tid] + ld_f(fb + F_SCH + tid) + b_attn[tid];
    float m = sc;
    for (int off = 32; off > 0; off >>= 1) m = fmaxf(m, __shfl_xor(m, off, 64));
    float ex = expf(sc - m);
    float sum = ex;
    for (int off = 32; off > 0; off >>= 1) sum += __shfl_xor(sum, off, 64);
    float a = ex / sum;
    st_f(fb + F_AW + tid, a);
    out_attns[s * LS + tid] = a;
  }
}

__global__ void __launch_bounds__(TPB, 1)
seq2seq_kernel(const int* __restrict__ qids, const int* __restrict__ cand,
               const float* __restrict__ enc_emb, const float* __restrict__ enc_Wih,
               const float* __restrict__ enc_Whh, const float* __restrict__ enc_bih,
               const float* __restrict__ enc_bhh, const float* __restrict__ dec_emb,
               const float* __restrict__ W_attn, const float* __restrict__ b_attn,
               const float* __restrict__ W_comb, const float* __restrict__ b_comb,
               const float* __restrict__ dWih, const float* __restrict__ dWhh,
               const float* __restrict__ dbih, const float* __restrict__ dbhh,
               const float* __restrict__ Wout, const float* __restrict__ bout,
               float* __restrict__ out, float* __restrict__ ws) {
  Ctrl* c = (Ctrl*)ws;
  float* fb = (float*)((char*)ws + CTRL_BYTES);
  const int tid = threadIdx.x;
  const int wg = blockIdx.x;
  const int wid = tid >> 6;
  const int lane = tid & 63;
  float* out_attns = out + (size_t)LS * VC;
  float* out_toks = out_attns + LS * LS;
  int bt = 0;

  __shared__ float s_h[3][HD];     // P2: staged h_{t-1} per encoder
  __shared__ float s_vec[HD];      // decode: staged x (G) / h2 (L)
  __shared__ float s_lv[4]; __shared__ int s_li[4];

#define GRID_BARRIER() do { ++bt; \
    if (wg == 0) { bar_master_wait(c, bt); bar_master_release(c, bt); } \
    else bar_worker(c, bt); } while (0)

  // ================= P1: gi GEMM (3 encoders) + WaE precompute ==============
  {
    int gw = wg * 4 + wid;
#pragma unroll 1
    for (int task = gw; task < 2304 + VC; task += GRID * 4) {
      if (task < 2304) {   // 4 rows of enc_W_ih x 64 timesteps
        int r0 = task * 4;
        int e = r0 / 3072;
        int rL = r0 - e * 3072;
        const float* Wr = enc_Wih + (size_t)e * 3 * HD * HD + (size_t)rL * HD;
        V16 w0 = ldv(Wr, lane), w1 = ldv(Wr + HD, lane);
        V16 w2 = ldv(Wr + 2 * HD, lane), w3 = ldv(Wr + 3 * HD, lane);
        const int* ids = (e == 0) ? qids : (cand + (e - 1) * LS);
        float b0 = enc_bih[e * 3 * HD + rL + 0];
        float b1 = enc_bih[e * 3 * HD + rL + 1];
        float b2 = enc_bih[e * 3 * HD + rL + 2];
        float b3 = enc_bih[e * 3 * HD + rL + 3];
#pragma unroll 1
        for (int t = 0; t < LS; ++t) {
          int tk = ids[t];
          V16 xv = ldv(enc_emb + ((size_t)e * VC + tk) * HD, lane);
          float s0 = dpp_sum63(dot16(w0, xv));
          float s1 = dpp_sum63(dot16(w1, xv));
          float s2 = dpp_sum63(dot16(w2, xv));
          float s3 = dpp_sum63(dot16(w3, xv));
          if (lane == 63) {
            float* dst = fb + F_GI + (size_t)(e * LS + t) * 3 * HD + rL;
            st_f2(dst, make_float2(s0 + b0, s1 + b1));
            st_f2(dst + 2, make_float2(s2 + b2, s3 + b3));
          }
        }
      } else {             // WaE row (token-major) for one vocab token
        int cc = task - 2304;
        V16 ev = ldv(dec_emb + (size_t)cc * HD, lane);
        float myval = 0.f;
#pragma unroll 1
        for (int k = 0; k < LS; k += 4) {
          float a0 = dot16(ldv(W_attn + (size_t)(k + 0) * 2 * HD, lane), ev);
          float a1 = dot16(ldv(W_attn + (size_t)(k + 1) * 2 * HD, lane), ev);
          float a2 = dot16(ldv(W_attn + (size_t)(k + 2) * 2 * HD, lane), ev);
          float a3 = dot16(ldv(W_attn + (size_t)(k + 3) * 2 * HD, lane), ev);
          a0 = bcast63(dpp_sum63(a0));
          a1 = bcast63(dpp_sum63(a1));
          a2 = bcast63(dpp_sum63(a2));
          a3 = bcast63(dpp_sum63(a3));
          myval = (lane == k + 0) ? a0 : myval;
          myval = (lane == k + 1) ? a1 : myval;
          myval = (lane == k + 2) ? a2 : myval;
          myval = (lane == k + 3) ? a3 : myval;
        }
        st_f(fb + F_WAE + (size_t)cc * LS + lane, myval);   // coalesced 256B
      }
    }
  }
  GRID_BARRIER();

  // ================= P2: encoder recurrence (64 steps, 3 encoders) ==========
#pragma unroll 1
  for (int t = 0; t < LS; ++t) {
    // stage h_{t-1} of all 3 encoders into LDS (sc-bypass reads)
#pragma unroll
    for (int k2 = 0; k2 < 6; ++k2) {
      int off = k2 * 256 + tid;          // float2 index in [0,1536)
      int e = off >> 9, rem = off & 511;
      float2 v = make_float2(0.f, 0.f);
      if (t > 0) v = ld_f2(fb + F_OUTS + (size_t)(e * LS + (t - 1)) * HD + rem * 2);
      *(float2*)&s_h[e][rem * 2] = v;
    }
    __syncthreads();
    int j = wg * 4 + wid;                // 1024 waves <-> hidden index j
#pragma unroll 1
    for (int e = 0; e < 3; ++e) {
      const float* Whh = enc_Whh + (size_t)e * 3 * HD * HD;
      V16 hv = ldv(&s_h[e][0], lane);
      float ghr = dpp_sum63(dot16(ldv(Whh + (size_t)j * HD, lane), hv));
      float ghz = dpp_sum63(dot16(ldv(Whh + (size_t)(HD + j) * HD, lane), hv));
      float ghn = dpp_sum63(dot16(ldv(Whh + (size_t)(2 * HD + j) * HD, lane), hv));
      if (lane == 63) {
        ghr += enc_bhh[e * 3 * HD + j];
        ghz += enc_bhh[e * 3 * HD + HD + j];
        ghn += enc_bhh[e * 3 * HD + 2 * HD + j];
        const float* gi = fb + F_GI + (size_t)(e * LS + t) * 3 * HD;
        float hp = s_h[e][j];
        st_f(fb + F_OUTS + (size_t)(e * LS + t) * HD + j,
             gru_out(gi[j], gi[HD + j], gi[2 * HD + j], ghr, ghz, ghn, hp));
      }
    }
    GRID_BARRIER();
  }

  // ===== P2b1: combine encoder outputs; init gh=b_hh, scoresH=0 =============
  {
    int gt = wg * TPB + tid;   // 0..65535
    float o0 = fb[F_OUTS + gt];
    float o1 = fb[F_OUTS + 65536 + gt];
    float o2 = fb[F_OUTS + 131072 + gt];
    st_f(fb + F_ENCOUT + gt, o0 + 0.5f * (o1 + o2));
    if (gt < 3 * HD) st_f(fb + F_GH + gt, dbhh[gt]);   // W_hh @ 0 + b_hh
    if (gt < LS) st_f(fb + F_SCH + gt, 0.f);           // W_attn[:,H:] @ 0
  }
  GRID_BARRIER();

  // ===== P2b2: M = W_comb[:, H:] @ enc_outs^T  (then prepare step 0) ========
  {
    int r = wg * 4 + wid;
    V16 wr = ldv(W_comb + (size_t)r * 2 * HD + HD, lane);
#pragma unroll 1
    for (int t = 0; t < LS; ++t) {
      float s = dpp_sum63(dot16(wr, ldv(fb + F_ENCOUT + (size_t)t * HD, lane)));
      if (lane == 63) st_f(fb + F_M + r * LS + t, s);
    }
  }
  ++bt;
  if (wg == 0) { bar_master_wait(c, bt); decode_prepare(0, c, fb, b_attn, out_attns, out_toks); bar_master_release(c, bt); }
  else bar_worker(c, bt);

  // ================= decode: 64 steps, 3 barriers each ======================
#pragma unroll 1
  for (int s = 0; s < LS; ++s) {
    int cp = ld_rlx(&c->copy);
    const int hcur = F_H + (s & 1) * HD;
    const int hnew = F_H + ((s + 1) & 1) * HD;

    // ---- Phase X: x = relu(W_comb[:, :H] @ e + M @ aw + b_comb)
    if (!cp) {
      int tok = ld_rlx(&c->tok);
      int r = wg * 4 + wid;
      V16 ev = ldv(dec_emb + (size_t)tok * HD, lane);
      V16 wr = ldv(W_comb + (size_t)r * 2 * HD, lane);
      float p = dot16(wr, ev);
      if (lane < 16) {
        float4 m4 = *(const float4*)(fb + F_M + r * LS + lane * 4);
        float2 a01 = ld_f2(fb + F_AW + lane * 4);
        float2 a23 = ld_f2(fb + F_AW + lane * 4 + 2);
        p = fmaf(m4.x, a01.x, p); p = fmaf(m4.y, a01.y, p);
        p = fmaf(m4.z, a23.x, p); p = fmaf(m4.w, a23.y, p);
      }
      float sum = dpp_sum63(p);
      if (lane == 63) st_f(fb + F_X + r, fmaxf(sum + b_comb[r], 0.f));
    }
    GRID_BARRIER();

    // ---- Phase G: gi = dec_W_ih @ x; h_new = GRU(h_cur, x)
    if (!cp) {
#pragma unroll
      for (int k2 = 0; k2 < 2; ++k2) {     // stage x into LDS
        int off = k2 * 256 + tid;
        *(float2*)&s_vec[off * 2] = ld_f2(fb + F_X + off * 2);
      }
      __syncthreads();
      int j = wg * 4 + wid;
      V16 xv = ldv(s_vec, lane);
      float g0 = dpp_sum63(dot16(ldv(dWih + (size_t)j * HD, lane), xv));
      float g1 = dpp_sum63(dot16(ldv(dWih + (size_t)(HD + j) * HD, lane), xv));
      float g2 = dpp_sum63(dot16(ldv(dWih + (size_t)(2 * HD + j) * HD, lane), xv));
      if (lane == 63) {
        g0 += dbih[j]; g1 += dbih[HD + j]; g2 += dbih[2 * HD + j];
        float ghr = ld_f(fb + F_GH + j);
        float ghz = ld_f(fb + F_GH + HD + j);
        float ghn = ld_f(fb + F_GH + 2 * HD + j);
        float hp = ld_f(fb + hcur + j);
        st_f(fb + hnew + j, gru_out(g0, g1, g2, ghr, ghz, ghn, hp));
      }
      __syncthreads();
    }
    GRID_BARRIER();

    // ---- Phase L: logits = W_out@h2 + b_out (+ speculative gh/scoresH on h2)
    if (cp) {
      if (tid < 125) {
        int i = wg * 125 + tid;
        st_f(out + (size_t)s * VC + i, out[(size_t)(s - 1) * VC + i]);
      }
    } else {
#pragma unroll
      for (int k2 = 0; k2 < 2; ++k2) {     // stage h2 into LDS
        int off = k2 * 256 + tid;
        *(float2*)&s_vec[off * 2] = ld_f2(fb + hnew + off * 2);
      }
      __syncthreads();
      V16 hv = ldv(s_vec, lane);
      for (int q = wid; q < 12; q += 4) {  // speculative dec_W_hh @ h2 + b_hh
        int row = wg * 12 + q;
        float g = dpp_sum63(dot16(ldv(dWhh + (size_t)row * HD, lane), hv));
        if (lane == 63) st_f(fb + F_GH + row, g + dbhh[row]);
      }
      if (wg < LS && wid == 0) {           // speculative W_attn[:,H:] @ h2
        float g = dpp_sum63(dot16(ldv(W_attn + (size_t)wg * 2 * HD + HD, lane), hv));
        if (lane == 63) st_f(fb + F_SCH + wg, g);
      }
      int base = wg * 125;
      int lo = wid * 32;
      int hi = (lo + 32 < 125) ? lo + 32 : 125;
      float bestv = -3.0e38f; int bestr = 0x7FFFFFFF;
#pragma unroll 1
      for (int rr = lo; rr < hi; rr += 4) {
        int i1 = (rr + 1 < hi) ? rr + 1 : hi - 1;
        int i2 = (rr + 2 < hi) ? rr + 2 : hi - 1;
        int i3 = (rr + 3 < hi) ? rr + 3 : hi - 1;
        int r0 = base + rr, r1 = base + i1, r2 = base + i2, r3 = base + i3;
        V16 w0 = ldv(Wout + (size_t)r0 * HD, lane);
        V16 w1 = ldv(Wout + (size_t)r1 * HD, lane);
        V16 w2 = ldv(Wout + (size_t)r2 * HD, lane);
        V16 w3 = ldv(Wout + (size_t)r3 * HD, lane);
        float p0 = dot16(w0, hv), p1 = dot16(w1, hv);
        float p2 = dot16(w2, hv), p3 = dot16(w3, hv);
        float v0 = bcast63(dpp_sum63(p0)) + bout[r0];
        float v1 = bcast63(dpp_sum63(p1)) + bout[r1];
        float v2 = bcast63(dpp_sum63(p2)) + bout[r2];
        float v3 = bcast63(dpp_sum63(p3)) + bout[r3];
        float sv = (lane == 0) ? v0 : (lane == 1) ? v1 : (lane == 2) ? v2 : v3;
        if (lane < 4 && rr + lane < hi)
          st_f(out + (size_t)s * VC + r0 + lane, sv);   // coalesced 16B
        if (v0 > bestv) { bestv = v0; bestr = r0; }
        if (v1 > bestv) { bestv = v1; bestr = r1; }
        if (v2 > bestv) { bestv = v2; bestr = r2; }
        if (v3 > bestv) { bestv = v3; bestr = r3; }
      }
      if (lane == 0) { s_lv[wid] = bestv; s_li[wid] = bestr; }
      __syncthreads();
      if (tid == 0) {
        float bv = s_lv[0]; int bi = s_li[0];
#pragma unroll
        for (int q2 = 1; q2 < 4; ++q2)
          if (s_lv[q2] > bv || (s_lv[q2] == bv && s_li[q2] < bi)) { bv = s_lv[q2]; bi = s_li[q2]; }
        st_f(fb + F_PARTV + wg, bv);
        st_rlx(&c->partIdx[wg], bi);
      }
    }
    ++bt;
    if (wg == 0) { bar_master_wait(c, bt); decode_prepare(s + 1, c, fb, b_attn, out_attns, out_toks); bar_master_release(c, bt); }
    else bar_worker(c, bt);
  }

  // ================= P4: in-place log_softmax per step row ==================
  if (wg < LS) {
    __shared__ float s_red[TPB];
    float* row = out + (size_t)wg * VC;
    float m = -3.0e38f;
    for (int i = tid; i < VC; i += TPB) m = fmaxf(m, row[i]);
    s_red[tid] = m; __syncthreads();
    for (int st = TPB / 2; st > 0; st >>= 1) {
      if (tid < st) s_red[tid] = fmaxf(s_red[tid], s_red[tid + st]);
      __syncthreads();
    }
    float rowmax = s_red[0]; __syncthreads();
    float sum = 0.f;
    for (int i = tid; i < VC; i += TPB) sum += expf(row[i] - rowmax);
    s_red[tid] = sum; __syncthreads();
    for (int st = TPB / 2; st > 0; st >>= 1) {
      if (tid < st) s_red[tid] += s_red[tid + st];
      __syncthreads();
    }
    float lse = rowmax + logf(s_red[0]);
    __syncthreads();
    for (int i = tid; i < VC; i += TPB) row[i] -= lse;
  }
}

extern "C" void kernel_launch(void* const* d_in, const int* in_sizes, int n_in,
                              void* d_out, int out_size, void* d_ws, size_t ws_size,
                              hipStream_t stream) {
  (void)in_sizes; (void)n_in; (void)out_size; (void)ws_size;
  // zero barrier state + both decoder hidden buffers (first 2048 floats of fb)
  hipMemsetAsync(d_ws, 0, CTRL_BYTES + 2 * HD * sizeof(float), stream);

  const int* qids = (const int*)d_in[0];
  const int* cand = (const int*)d_in[1];
  const float* enc_emb = (const float*)d_in[2];
  const float* enc_Wih = (const float*)d_in[3];
  const float* enc_Whh = (const float*)d_in[4];
  const float* enc_bih = (const float*)d_in[5];
  const float* enc_bhh = (const float*)d_in[6];
  const float* dec_emb = (const float*)d_in[7];
  const float* W_attn = (const float*)d_in[8];
  const float* b_attn = (const float*)d_in[9];
  const float* W_comb = (const float*)d_in[10];
  const float* b_comb = (const float*)d_in[11];
  const float* dWih = (const float*)d_in[12];
  const float* dWhh = (const float*)d_in[13];
  const float* dbih = (const float*)d_in[14];
  const float* dbhh = (const float*)d_in[15];
  const float* Wout = (const float*)d_in[16];
  const float* bout = (const float*)d_in[17];
  float* outp = (float*)d_out;
  float* wsp = (float*)d_ws;

  void* args[] = { &qids, &cand, &enc_emb, &enc_Wih, &enc_Whh, &enc_bih, &enc_bhh,
                   &dec_emb, &W_attn, &b_attn, &W_comb, &b_comb, &dWih, &dWhh,
                   &dbih, &dbhh, &Wout, &bout, &outp, &wsp };
  hipLaunchCooperativeKernel(reinterpret_cast<void*>(seq2seq_kernel),
                             dim3(GRID), dim3(TPB), args, 0, stream);
}